// Round 10
// baseline (601.109 us; speedup 1.0000x reference)
//
#include <hip/hip_runtime.h>
#include <math.h>

#define TPB 512
static constexpr int N0  = 64;   // nodes per graph
static constexpr int H   = 128;  // hidden
static constexpr int XLD = 132;  // LDS row stride for feature tiles (16B aligned, bank-skewed)
static constexpr int NW  = TPB / 64;  // waves per block

#define SCHED_FENCE() __builtin_amdgcn_sched_barrier(0)

typedef const __attribute__((address_space(1))) unsigned int glb_u32;
typedef __attribute__((address_space(3))) unsigned int lds_u32;

// 52.7 KB/block -> 3 blocks/CU; with TPB=512 that is 24 waves/CU (6/SIMD).
struct alignas(16) Shm {
  unsigned long long adjM[N0];  // 512 B   adjacency bitmask rows (no self loops)
  float Xs[N0 * XLD];           // 33792 B ping buffer (+ W dbuf in dead rows)
  float Zs[32 * XLD];           // 16896 B pong buffer (z1; MLP scratch)
  float uu[N0];                 // u = x.wl
  float sv[N0];                 // v then score
  float tv[N0];                 // tanh(score) of selected
  float dinv[N0];
  int   sel[N0];
};

template<int W>
__device__ __forceinline__ float redsum(float v) {
  #pragma unroll
  for (int m = W >> 1; m; m >>= 1) v += __shfl_xor(v, m, 64);
  return v;
}
template<int W>
__device__ __forceinline__ int redsum_i(int v) {
  #pragma unroll
  for (int m = W >> 1; m; m >>= 1) v += __shfl_xor(v, m, 64);
  return v;
}

// z[i][k] = dinv[i] * sum_{j in nbr(i) U {i}} dinv[j] * x[j][k]   (adj entries are {0,1})
template<int NN, int NCH, int KCH>
__device__ __forceinline__ void norm_agg(const Shm& sh, const float* x, int xld,
                                         float* z, int zld, int tid) {
  #pragma unroll 1
  for (int it = tid; it < NN * NCH; it += TPB) {
    int i = it & (NN - 1);
    int g = it / NN;
    unsigned long long m = sh.adjM[i] | (1ull << i);  // A + I (diag of A is 0)
    float acc[KCH];
    #pragma unroll
    for (int c = 0; c < KCH; ++c) acc[c] = 0.f;
    #pragma unroll 1
    while (m) {
      int j = __builtin_ctzll(m); m &= m - 1;
      float a = sh.dinv[j];
      const float* xp = x + j * xld + g * KCH;
      #pragma unroll
      for (int c = 0; c < KCH; c += 4) {
        float4 xv = *(const float4*)(xp + c);
        acc[c]     += a * xv.x; acc[c + 1] += a * xv.y;
        acc[c + 2] += a * xv.z; acc[c + 3] += a * xv.w;
      }
    }
    float di = sh.dinv[i];
    #pragma unroll
    for (int c = 0; c < KCH; c += 4) {
      float4 r = make_float4(acc[c] * di, acc[c + 1] * di, acc[c + 2] * di, acc[c + 3] * di);
      *(float4*)(z + i * zld + g * KCH + c) = r;
    }
  }
}

// Async DMA one W tile into LDS. Each WAVE moves 1024B chunks (64 lanes x 16B);
// LDS dest wave-uniform, global src per-lane.
template<int KT>
__device__ __forceinline__ void stage_async(const float* gsrc, float* ldst, int wv, int ln) {
  constexpr int CH_TOT = (KT * H) / 256;   // number of 1024B chunks
  #pragma unroll
  for (int q = 0; q * NW < CH_TOT; ++q) {
    int chunk = q * NW + wv;
    if (chunk < CH_TOT) {
      __builtin_amdgcn_global_load_lds(
          (glb_u32*)(gsrc + chunk * 256 + ln * 4),
          (lds_u32*)(ldst + chunk * 256),
          16, 0, 0);
    }
  }
}

// out[i][f] = relu(sum_k z[i][k]*W[k][f] + b[f]).
// Double-buffered async W staging; one vmcnt(0)+barrier per tile.
// 512 thr = 8 row-groups x 64 f (2 cols each).
template<int R, int K, int KREAL, int KT>
__device__ __forceinline__ void gemm_dbuf(const float* z, int zld,
    float* wt0, float* wt1,
    const float* __restrict__ Wg, const float* __restrict__ bg,
    float* out, int old_, int tid) {
  constexpr int NR = R / 8;
  const int f  = tid & 63;
  const int r0 = (tid >> 6) * NR;
  const int wv = tid >> 6;
  const int ln = tid & 63;
  float acc0[NR], acc1[NR];
  #pragma unroll
  for (int r = 0; r < NR; ++r) { acc0[r] = 0.f; acc1[r] = 0.f; }
  stage_async<KT>(Wg, wt0, wv, ln);
  asm volatile("s_waitcnt vmcnt(0)" ::: "memory");
  __syncthreads();
  #pragma unroll 1
  for (int kt = 0; kt < K; kt += KT) {
    const int t = kt / KT;
    const float* cur = (t & 1) ? wt1 : wt0;
    float* nxt = (t & 1) ? wt0 : wt1;
    if (kt + KT < K) {
      const int nk = kt + KT;
      if (nk + KT <= KREAL) {
        stage_async<KT>(Wg + nk * H, nxt, wv, ln);
      } else {
        // bounds-checked sync staging with zero pad (stage-1 tail only)
        #pragma unroll 1
        for (int e = tid * 4; e < KT * H; e += TPB * 4) {
          int row = e >> 7, col = e & (H - 1);
          float4 v = make_float4(0.f, 0.f, 0.f, 0.f);
          if (nk + row < KREAL) v = *(const float4*)(Wg + (nk + row) * H + col);
          *(float4*)(nxt + e) = v;
        }
      }
    }
    const int kn = (K - kt < KT) ? (K - kt) : KT;
    float w0[KT], w1[KT];
    #pragma unroll
    for (int k = 0; k < KT; ++k) {
      w0[k] = cur[k * H + f];
      w1[k] = cur[k * H + f + 64];
    }
    #pragma unroll
    for (int r = 0; r < NR; ++r) {
      const float* zr = z + (r0 + r) * zld + kt;
      #pragma unroll
      for (int k = 0; k < KT; k += 4) {
        if (k < kn) {
          float4 zv = *(const float4*)(zr + k);
          acc0[r] += zv.x * w0[k] + zv.y * w0[k + 1] + zv.z * w0[k + 2] + zv.w * w0[k + 3];
          acc1[r] += zv.x * w1[k] + zv.y * w1[k + 1] + zv.z * w1[k + 2] + zv.w * w1[k + 3];
        }
      }
    }
    asm volatile("s_waitcnt vmcnt(0)" ::: "memory");
    __syncthreads();
  }
  const float b0 = bg[f], b1 = bg[f + 64];
  #pragma unroll
  for (int r = 0; r < NR; ++r) {
    out[(r0 + r) * old_ + f]      = fmaxf(acc0[r] + b0, 0.f);
    out[(r0 + r) * old_ + f + 64] = fmaxf(acc1[r] + b1, 0.f);
  }
}

// SAGPool(NN->KK) + bitmask adjacency filter + next dinv + register readout accum.
// UVP = TPB/(2*NN); RKP lanes per rank row (groups may exceed NN -> guarded).
template<int NN, int KK, int UVP, int RKP, bool DODINV>
__device__ __forceinline__ void sag_pool_readout(Shm& sh,
    const float* x, float* xn,
    const float* __restrict__ wl, const float* __restrict__ blp,
    const float* __restrict__ wr, int tid, float& rm, float& rs) {
  { // u[j]=x[j].wl -> uu, v[j]=x[j].wr -> sv  (2*NN*UVP == TPB)
    int dot = tid / UVP, p = tid % UVP;
    int j = dot >> 1;
    const float* wp = (dot & 1) ? wr : wl;
    constexpr int CH = H / UVP;
    const float* xr = x + j * XLD + p * CH;
    const float* wq = wp + p * CH;
    float a = 0.f;
    #pragma unroll
    for (int k = 0; k < CH; k += 4) {
      float4 xv = *(const float4*)(xr + k);
      float4 wv = *(const float4*)(wq + k);
      a += xv.x * wv.x + xv.y * wv.y + xv.z * wv.z + xv.w * wv.w;
    }
    a = redsum<UVP>(a);
    if (p == 0) { if (dot & 1) sh.sv[j] = a; else sh.uu[j] = a; }
  }
  __syncthreads();
  SCHED_FENCE();
  // s[i] = sum_{j in nbr(i)} u[j] + bl + v[i]   (v already in sv[i]; RMW own slot)
  if (tid < NN) {
    unsigned long long m = sh.adjM[tid];
    float a = blp[0] + sh.sv[tid];
    #pragma unroll 1
    while (m) { int j = __builtin_ctzll(m); m &= m - 1; a += sh.uu[j]; }
    sh.sv[tid] = a;
  }
  __syncthreads();
  { // exact stable top-k via parallel rank counting
    int i = tid / RKP, p = tid % RKP;
    if (i < NN) {
      constexpr int CHr = NN / RKP > 0 ? NN / RKP : 1;
      float si = sh.sv[i];
      int cnt = 0;
      #pragma unroll
      for (int c = 0; c < CHr; ++c) {
        int j = p * CHr + c;
        if (j < NN) {
          float sj = sh.sv[j];
          cnt += (sj > si || (sj == si && j < i)) ? 1 : 0;
        }
      }
      cnt = redsum_i<RKP>(cnt);
      if (p == 0 && cnt < KK) { sh.sel[cnt] = i; sh.tv[cnt] = tanhf(si); }
    }
  }
  __syncthreads();
  SCHED_FENCE();
  // phase A: gather x_next = x[sel]*tanh(s[sel]); snapshot old adj rows in regs
  unsigned long long oldrow = 0ull;
  if (tid < KK) oldrow = sh.adjM[sh.sel[tid]];
  constexpr int HV = H / 4;
  #pragma unroll 1
  for (int e = tid; e < KK * HV; e += TPB) {
    int r = e / HV, c = (e % HV) * 4;
    float4 v = *(const float4*)(x + sh.sel[r] * XLD + c);
    float t = sh.tv[r];
    *(float4*)(xn + r * XLD + c) = make_float4(v.x * t, v.y * t, v.z * t, v.w * t);
  }
  __syncthreads();
  // phase B: filtered bitmask adjacency + next dinv; readout accumulate (regs)
  if (tid < KK) {
    unsigned long long nm = 0ull;
    #pragma unroll 1
    for (int c = 0; c < KK; ++c)
      nm |= ((oldrow >> sh.sel[c]) & 1ull) << c;
    sh.adjM[tid] = nm;
    if (DODINV) sh.dinv[tid] = rsqrtf(1.f + (float)__popcll(nm));
  }
  if (tid < H) {
    float m = -INFINITY, s = 0.f;
    #pragma unroll
    for (int r = 0; r < KK; ++r) {
      float v = xn[r * XLD + tid];
      m = fmaxf(m, v); s += v;
    }
    rm += m;
    rs += s * (1.f / KK);
  }
  __syncthreads();
  SCHED_FENCE();
}

__global__ __launch_bounds__(TPB, 3) void sagpool_fused(
    const int* __restrict__ aa, const float* __restrict__ pos,
    const float* __restrict__ cdr, const float* __restrict__ adjG,
    const float* __restrict__ emb,
    const float* __restrict__ W1, const float* __restrict__ b1,
    const float* __restrict__ p1wl, const float* __restrict__ p1bl, const float* __restrict__ p1wr,
    const float* __restrict__ W2, const float* __restrict__ b2,
    const float* __restrict__ p2wl, const float* __restrict__ p2bl, const float* __restrict__ p2wr,
    const float* __restrict__ W3, const float* __restrict__ b3,
    const float* __restrict__ p3wl, const float* __restrict__ p3bl, const float* __restrict__ p3wr,
    const float* __restrict__ mW1, const float* __restrict__ mb1,
    const float* __restrict__ mW2, const float* __restrict__ mb2,
    const float* __restrict__ mW3, const float* __restrict__ mb3,
    float* __restrict__ out)
{
  __shared__ Shm sh;
  const int b   = blockIdx.x;
  const int tid = threadIdx.x;

  float rm = 0.f, rs = 0.f;   // readout accumulators (feature f = tid, tid < 128)

  // adjacency [64][64] -> 64-bit row masks + fused degree/dinv (8 lanes/row)
  {
    const float* rp = adjG + (size_t)b * (N0 * N0) + (tid >> 3) * N0 + (tid & 7) * 8;
    float4 v0 = *(const float4*)(rp);
    float4 v1 = *(const float4*)(rp + 4);
    unsigned int bits = (v0.x != 0.f ? 1u : 0u)  | (v0.y != 0.f ? 2u : 0u)
                      | (v0.z != 0.f ? 4u : 0u)  | (v0.w != 0.f ? 8u : 0u)
                      | (v1.x != 0.f ? 16u : 0u) | (v1.y != 0.f ? 32u : 0u)
                      | (v1.z != 0.f ? 64u : 0u) | (v1.w != 0.f ? 128u : 0u);
    unsigned long long mpart = (unsigned long long)bits << ((tid & 7) * 8);
    mpart |= __shfl_xor(mpart, 1, 64);
    mpart |= __shfl_xor(mpart, 2, 64);
    mpart |= __shfl_xor(mpart, 4, 64);
    if ((tid & 7) == 0) {
      int r = tid >> 3;
      sh.adjM[r] = mpart;
      sh.dinv[r] = rsqrtf(1.f + (float)__popcll(mpart));
    }
  }
  SCHED_FENCE();
  // build x = [emb[aa] | pos | is_cdr3 | 0 0] into Xs cols 0..35
  #pragma unroll 1
  for (int e = tid; e < N0 * 36; e += TPB) {
    int j = e / 36, k = e - j * 36;
    int node = b * N0 + j;
    float v;
    if (k < 32)       v = emb[aa[node] * 32 + k];
    else if (k == 32) v = pos[node];
    else if (k == 33) v = cdr[node];
    else              v = 0.f;
    sh.Xs[j * XLD + k] = v;
  }
  __syncthreads();
  SCHED_FENCE();

  // ---- stage 1: GCN(34->128) on 64 nodes, pool 64->32 ----
  norm_agg<64, 9, 4>(sh, sh.Xs, XLD, sh.Zs, 36, tid);   // 576 items
  __syncthreads();
  SCHED_FENCE();
  gemm_dbuf<64, 36, 34, 8>(sh.Zs, 36, sh.Xs + 48 * XLD, sh.Xs + 48 * XLD + 1024,
                           W1, b1, sh.Xs, XLD, tid);
  __syncthreads();
  SCHED_FENCE();
  sag_pool_readout<64, 32, 4, 8, true>(sh, sh.Xs, sh.Zs, p1wl, p1bl, p1wr, tid, rm, rs);

  // ---- stage 2: GCN(128->128) on 32 nodes, pool 32->16 ----
  norm_agg<32, 16, 8>(sh, sh.Zs, XLD, sh.Xs, XLD, tid); // 512 items
  __syncthreads();
  SCHED_FENCE();
  gemm_dbuf<32, 128, 128, 16>(sh.Xs, XLD, sh.Xs + 32 * XLD, sh.Xs + 48 * XLD,
                              W2, b2, sh.Zs, XLD, tid);
  __syncthreads();
  SCHED_FENCE();
  sag_pool_readout<32, 16, 8, 16, true>(sh, sh.Zs, sh.Xs, p2wl, p2bl, p2wr, tid, rm, rs);

  // ---- stage 3: GCN(128->128) on 16 nodes, pool 16->8 ----
  norm_agg<16, 32, 4>(sh, sh.Xs, XLD, sh.Zs, XLD, tid); // 512 items
  __syncthreads();
  SCHED_FENCE();
  gemm_dbuf<16, 128, 128, 16>(sh.Zs, XLD, sh.Xs + 32 * XLD, sh.Xs + 48 * XLD,
                              W3, b3, sh.Xs, XLD, tid);
  __syncthreads();
  SCHED_FENCE();
  sag_pool_readout<16, 8, 16, 16, false>(sh, sh.Xs, sh.Zs, p3wl, p3bl, p3wr, tid, rm, rs);

  // ---- MLP head ----
  // Zs dead. Layout: rbuf [0..256) | h1 [256..384) | h1p [384..896) | h2p [896..1408)
  if (tid < H) { sh.Zs[tid] = rm; sh.Zs[H + tid] = rs; }
  __syncthreads();
  SCHED_FENCE();
  { // h1 partials: 128 f x 4 k-quarters
    int f = tid & (H - 1), p = tid >> 7;
    const int base = p * 64;
    float a = 0.f;
    #pragma unroll 4
    for (int k = 0; k < 64; ++k) a += sh.Zs[base + k] * mW1[(base + k) * H + f];
    sh.Zs[384 + p * H + f] = a;
  }
  __syncthreads();
  SCHED_FENCE();
  if (tid < H) {
    float a = mb1[tid] + sh.Zs[384 + tid] + sh.Zs[384 + H + tid]
            + sh.Zs[384 + 2 * H + tid] + sh.Zs[384 + 3 * H + tid];
    sh.Zs[256 + tid] = fmaxf(a, 0.f);
  }
  __syncthreads();
  SCHED_FENCE();
  { // h2 partials: 64 o x 8 k-parts
    int o = tid & 63, p = tid >> 6;
    const int base = p * 16;
    float a = 0.f;
    #pragma unroll 4
    for (int k = 0; k < 16; ++k) a += sh.Zs[256 + base + k] * mW2[(base + k) * 64 + o];
    sh.Zs[896 + p * 64 + o] = a;
  }
  __syncthreads();
  SCHED_FENCE();
  if (tid < 64) {
    float a = 0.f;
    #pragma unroll
    for (int q = 0; q < 8; ++q) a += sh.Zs[896 + q * 64 + tid];
    a = fmaxf(a + mb2[tid], 0.f);
    float v = a * mW3[tid];
    v = redsum<64>(v);
    if (tid == 0) out[b] = v + mb3[0];
  }
}

extern "C" void kernel_launch(void* const* d_in, const int* in_sizes, int n_in,
                              void* d_out, int out_size, void* d_ws, size_t ws_size,
                              hipStream_t stream) {
  (void)n_in; (void)d_ws; (void)ws_size; (void)out_size;
  const int*   aa   = (const int*)  d_in[0];
  const float* pos  = (const float*)d_in[1];
  const float* cdr  = (const float*)d_in[2];
  const float* adj  = (const float*)d_in[3];
  const float* emb  = (const float*)d_in[4];
  const float* W1   = (const float*)d_in[5];
  const float* b1   = (const float*)d_in[6];
  const float* p1wl = (const float*)d_in[7];
  const float* p1bl = (const float*)d_in[8];
  const float* p1wr = (const float*)d_in[9];
  const float* W2   = (const float*)d_in[10];
  const float* b2   = (const float*)d_in[11];
  const float* p2wl = (const float*)d_in[12];
  const float* p2bl = (const float*)d_in[13];
  const float* p2wr = (const float*)d_in[14];
  const float* W3   = (const float*)d_in[15];
  const float* b3   = (const float*)d_in[16];
  const float* p3wl = (const float*)d_in[17];
  const float* p3bl = (const float*)d_in[18];
  const float* p3wr = (const float*)d_in[19];
  const float* mW1  = (const float*)d_in[20];
  const float* mb1  = (const float*)d_in[21];
  const float* mW2  = (const float*)d_in[22];
  const float* mb2  = (const float*)d_in[23];
  const float* mW3  = (const float*)d_in[24];
  const float* mb3  = (const float*)d_in[25];
  float* out = (float*)d_out;

  const int B = in_sizes[0] / N0;  // 4096
  hipLaunchKernelGGL(sagpool_fused, dim3(B), dim3(TPB), 0, stream,
                     aa, pos, cdr, adj, emb,
                     W1, b1, p1wl, p1bl, p1wr,
                     W2, b2, p2wl, p2bl, p2wr,
                     W3, b3, p3wl, p3bl, p3wr,
                     mW1, mb1, mW2, mb2, mW3, mb3, out);
}

// Round 11
// 284.495 us; speedup vs baseline: 2.1129x; 2.1129x over previous
//
#include <hip/hip_runtime.h>
#include <math.h>

#define TPB 256
static constexpr int N0  = 64;   // nodes per graph
static constexpr int H   = 128;  // hidden
static constexpr int XLD = 132;  // LDS row stride for feature tiles (16B aligned, bank-skewed)

#define SCHED_FENCE() __builtin_amdgcn_sched_barrier(0)

// No stored y1: stage-1 pooling projections computed in-GEMM, selected rows
// recomputed. W read from global (L2-hot) with register double-buffering.
// LDS = 2 ping-pong buffers + misc = 35.6 KB -> 4 blocks/CU (16 waves).
struct alignas(16) Shm {
  unsigned long long adjM[N0];  // 512 B  adjacency bitmask rows (no self loops)
  float RA[32 * XLD];           // 16896 B  z1[64][36] / z2 / x3 / y3 / MLP scratch
  float RB[32 * XLD];           // 16896 B  xin[64][36] / x2 / y2 / z3 / x4
  float uu[N0];                 // u = y.wl
  float sv[N0];                 // v then score
  float tv[N0];                 // tanh(score) of selected
  float dinv[N0];
  int   sel[N0];
};

template<int W>
__device__ __forceinline__ float redsum(float v) {
  #pragma unroll
  for (int m = W >> 1; m; m >>= 1) v += __shfl_xor(v, m, 64);
  return v;
}
template<int W>
__device__ __forceinline__ int redsum_i(int v) {
  #pragma unroll
  for (int m = W >> 1; m; m >>= 1) v += __shfl_xor(v, m, 64);
  return v;
}

// z[i][k] = dinv[i] * sum_{j in nbr(i) U {i}} dinv[j] * x[j][k]   (adj entries are {0,1})
template<int NN, int NCH, int KCH>
__device__ __forceinline__ void norm_agg(const Shm& sh, const float* x, int xld,
                                         float* z, int zld, int tid) {
  #pragma unroll 1
  for (int it = tid; it < NN * NCH; it += TPB) {
    int i = it & (NN - 1);
    int g = it / NN;
    unsigned long long m = sh.adjM[i] | (1ull << i);  // A + I (diag of A is 0)
    float acc[KCH];
    #pragma unroll
    for (int c = 0; c < KCH; ++c) acc[c] = 0.f;
    #pragma unroll 1
    while (m) {
      int j = __builtin_ctzll(m); m &= m - 1;
      float a = sh.dinv[j];
      const float* xp = x + j * xld + g * KCH;
      #pragma unroll
      for (int c = 0; c < KCH; c += 4) {
        float4 xv = *(const float4*)(xp + c);
        acc[c]     += a * xv.x; acc[c + 1] += a * xv.y;
        acc[c + 2] += a * xv.z; acc[c + 3] += a * xv.w;
      }
    }
    float di = sh.dinv[i];
    #pragma unroll
    for (int c = 0; c < KCH; c += 4) {
      float4 r = make_float4(acc[c] * di, acc[c + 1] * di, acc[c + 2] * di, acc[c + 3] * di);
      *(float4*)(z + i * zld + g * KCH + c) = r;
    }
  }
}

// GEMM with W streamed from global memory, register double-buffered in KC-chunks.
// Threads: f = tid&63 (cols f, f+64), rg = tid>>6 (4 row groups of NR = R/4).
// MODE 0: out[r][f] = relu(acc + b)              (stages 2,3)
// MODE 1: no out; u/v = row-dot with wl/wr via redsum<64> -> uu, sv   (stage 1)
// MODE 2: rows gathered via sel; out[r][f] = relu(acc + b) * tv[r]    (recompute)
// K may be padded past KREAL (zero-w guard); z rows must have >= K readable floats
// within the LDS region (junk x 0 is harmless).
template<int R, int K, int KREAL, int KC, int MODE>
__device__ __forceinline__ void gemm_gw(Shm& sh, const float* z, int zld,
    const float* __restrict__ Wg, const float* __restrict__ bg,
    float* out, int old_,
    const float* __restrict__ wl, const float* __restrict__ wr,
    int tid) {
  constexpr int NR = R / 4;
  const int f  = tid & 63;
  const int r0 = (tid >> 6) * NR;
  float acc0[NR], acc1[NR];
  int zoff[NR];
  #pragma unroll
  for (int r = 0; r < NR; ++r) {
    acc0[r] = 0.f; acc1[r] = 0.f;
    int row = (MODE == 2) ? sh.sel[r0 + r] : (r0 + r);
    zoff[r] = row * zld;
  }
  float w0[KC], w1[KC], nw0[KC], nw1[KC];
  #pragma unroll
  for (int k = 0; k < KC; ++k) {
    w0[k] = (k < KREAL) ? Wg[k * H + f] : 0.f;
    w1[k] = (k < KREAL) ? Wg[k * H + f + 64] : 0.f;
  }
  #pragma unroll 1
  for (int kt = 0; kt < K; kt += KC) {
    if (kt + KC < K) {   // prefetch next W chunk into nw while FMAs use w
      #pragma unroll
      for (int k = 0; k < KC; ++k) {
        int gr = kt + KC + k;
        nw0[k] = (gr < KREAL) ? Wg[gr * H + f] : 0.f;
        nw1[k] = (gr < KREAL) ? Wg[gr * H + f + 64] : 0.f;
      }
    }
    #pragma unroll
    for (int r = 0; r < NR; ++r) {
      const float* zr = z + zoff[r] + kt;
      #pragma unroll
      for (int k = 0; k < KC; k += 4) {
        float4 zv = *(const float4*)(zr + k);
        acc0[r] += zv.x * w0[k] + zv.y * w0[k + 1] + zv.z * w0[k + 2] + zv.w * w0[k + 3];
        acc1[r] += zv.x * w1[k] + zv.y * w1[k + 1] + zv.z * w1[k + 2] + zv.w * w1[k + 3];
      }
    }
    #pragma unroll
    for (int k = 0; k < KC; ++k) { w0[k] = nw0[k]; w1[k] = nw1[k]; }
  }
  const float b0 = bg[f], b1 = bg[f + 64];
  if constexpr (MODE == 1) {
    const float wl0 = wl[f], wl1 = wl[f + 64];
    const float wr0 = wr[f], wr1 = wr[f + 64];
    #pragma unroll
    for (int r = 0; r < NR; ++r) {
      float y0 = fmaxf(acc0[r] + b0, 0.f);
      float y1 = fmaxf(acc1[r] + b1, 0.f);
      float up = y0 * wl0 + y1 * wl1;
      float vp = y0 * wr0 + y1 * wr1;
      up = redsum<64>(up);
      vp = redsum<64>(vp);
      if (f == 0) { sh.uu[r0 + r] = up; sh.sv[r0 + r] = vp; }
    }
  } else if constexpr (MODE == 2) {
    #pragma unroll
    for (int r = 0; r < NR; ++r) {
      float t = sh.tv[r0 + r];
      out[(r0 + r) * old_ + f]      = fmaxf(acc0[r] + b0, 0.f) * t;
      out[(r0 + r) * old_ + f + 64] = fmaxf(acc1[r] + b1, 0.f) * t;
    }
  } else {
    #pragma unroll
    for (int r = 0; r < NR; ++r) {
      out[(r0 + r) * old_ + f]      = fmaxf(acc0[r] + b0, 0.f);
      out[(r0 + r) * old_ + f + 64] = fmaxf(acc1[r] + b1, 0.f);
    }
  }
}

// SAGPool(NN->KK) for stages 2/3 (y stored in LDS) — from R9, unchanged.
template<int NN, int KK, int UVP, int RKP, bool DODINV>
__device__ __forceinline__ void sag_pool_readout(Shm& sh,
    const float* x, float* xn,
    const float* __restrict__ wl, const float* __restrict__ blp,
    const float* __restrict__ wr, int tid, float& rm, float& rs) {
  { // u[j]=x[j].wl -> uu, v[j]=x[j].wr -> sv  (2*NN*UVP == TPB)
    int dot = tid / UVP, p = tid % UVP;
    int j = dot >> 1;
    const float* wp = (dot & 1) ? wr : wl;
    constexpr int CH = H / UVP;
    const float* xr = x + j * XLD + p * CH;
    const float* wq = wp + p * CH;
    float a = 0.f;
    #pragma unroll
    for (int k = 0; k < CH; k += 4) {
      float4 xv = *(const float4*)(xr + k);
      float4 wv = *(const float4*)(wq + k);
      a += xv.x * wv.x + xv.y * wv.y + xv.z * wv.z + xv.w * wv.w;
    }
    a = redsum<UVP>(a);
    if (p == 0) { if (dot & 1) sh.sv[j] = a; else sh.uu[j] = a; }
  }
  __syncthreads();
  SCHED_FENCE();
  if (tid < NN) {
    unsigned long long m = sh.adjM[tid];
    float a = blp[0] + sh.sv[tid];
    #pragma unroll 1
    while (m) { int j = __builtin_ctzll(m); m &= m - 1; a += sh.uu[j]; }
    sh.sv[tid] = a;
  }
  __syncthreads();
  { // exact stable top-k via parallel rank counting (NN*RKP == TPB)
    int i = tid / RKP, p = tid % RKP;
    constexpr int CHr = NN / RKP;
    float si = sh.sv[i];
    int cnt = 0;
    #pragma unroll
    for (int c = 0; c < CHr; ++c) {
      int j = p * CHr + c;
      float sj = sh.sv[j];
      cnt += (sj > si || (sj == si && j < i)) ? 1 : 0;
    }
    cnt = redsum_i<RKP>(cnt);
    if (p == 0 && cnt < KK) { sh.sel[cnt] = i; sh.tv[cnt] = tanhf(si); }
  }
  __syncthreads();
  SCHED_FENCE();
  unsigned long long oldrow = 0ull;
  if (tid < KK) oldrow = sh.adjM[sh.sel[tid]];
  constexpr int HV = H / 4;
  #pragma unroll 1
  for (int e = tid; e < KK * HV; e += TPB) {
    int r = e / HV, c = (e % HV) * 4;
    float4 v = *(const float4*)(x + sh.sel[r] * XLD + c);
    float t = sh.tv[r];
    *(float4*)(xn + r * XLD + c) = make_float4(v.x * t, v.y * t, v.z * t, v.w * t);
  }
  __syncthreads();
  if (tid < KK) {
    unsigned long long nm = 0ull;
    #pragma unroll 1
    for (int c = 0; c < KK; ++c)
      nm |= ((oldrow >> sh.sel[c]) & 1ull) << c;
    sh.adjM[tid] = nm;
    if (DODINV) sh.dinv[tid] = rsqrtf(1.f + (float)__popcll(nm));
  }
  if (tid < H) {
    float m = -INFINITY, s = 0.f;
    #pragma unroll
    for (int r = 0; r < KK; ++r) {
      float v = xn[r * XLD + tid];
      m = fmaxf(m, v); s += v;
    }
    rm += m;
    rs += s * (1.f / KK);
  }
  __syncthreads();
  SCHED_FENCE();
}

__global__ __launch_bounds__(TPB, 4) void sagpool_fused(
    const int* __restrict__ aa, const float* __restrict__ pos,
    const float* __restrict__ cdr, const float* __restrict__ adjG,
    const float* __restrict__ emb,
    const float* __restrict__ W1, const float* __restrict__ b1,
    const float* __restrict__ p1wl, const float* __restrict__ p1bl, const float* __restrict__ p1wr,
    const float* __restrict__ W2, const float* __restrict__ b2,
    const float* __restrict__ p2wl, const float* __restrict__ p2bl, const float* __restrict__ p2wr,
    const float* __restrict__ W3, const float* __restrict__ b3,
    const float* __restrict__ p3wl, const float* __restrict__ p3bl, const float* __restrict__ p3wr,
    const float* __restrict__ mW1, const float* __restrict__ mb1,
    const float* __restrict__ mW2, const float* __restrict__ mb2,
    const float* __restrict__ mW3, const float* __restrict__ mb3,
    float* __restrict__ out)
{
  __shared__ Shm sh;
  const int b   = blockIdx.x;
  const int tid = threadIdx.x;

  float rm = 0.f, rs = 0.f;   // readout accumulators (feature f = tid, tid < 128)

  // adjacency [64][64] -> 64-bit row masks + fused degree/dinv (4 lanes/row)
  {
    const float* rp = adjG + (size_t)b * (N0 * N0) + (tid >> 2) * N0 + (tid & 3) * 16;
    unsigned long long mpart = 0ull;
    #pragma unroll
    for (int q = 0; q < 16; q += 4) {
      float4 v = *(const float4*)(rp + q);
      unsigned int bits = (v.x != 0.f ? 1u : 0u) | (v.y != 0.f ? 2u : 0u)
                        | (v.z != 0.f ? 4u : 0u) | (v.w != 0.f ? 8u : 0u);
      mpart |= (unsigned long long)bits << q;
    }
    mpart <<= ((tid & 3) * 16);
    mpart |= __shfl_xor(mpart, 1, 64);
    mpart |= __shfl_xor(mpart, 2, 64);
    if ((tid & 3) == 0) {
      int r = tid >> 2;
      sh.adjM[r] = mpart;
      sh.dinv[r] = rsqrtf(1.f + (float)__popcll(mpart));
    }
  }
  SCHED_FENCE();
  // build xin = [emb[aa] | pos | is_cdr3 | 0 0] -> RB [64][36] packed
  #pragma unroll 1
  for (int e = tid; e < N0 * 36; e += TPB) {
    int j = e / 36, k = e - j * 36;
    int node = b * N0 + j;
    float v;
    if (k < 32)       v = emb[aa[node] * 32 + k];
    else if (k == 32) v = pos[node];
    else if (k == 33) v = cdr[node];
    else              v = 0.f;
    sh.RB[e] = v;
  }
  __syncthreads();
  SCHED_FENCE();

  // ---- stage 1: GCN(34->128) on 64 nodes, pool 64->32 (y1 never stored) ----
  norm_agg<64, 3, 12>(sh, sh.RB, 36, sh.RA, 36, tid);   // xin -> z1 (RA)
  __syncthreads();
  SCHED_FENCE();
  // y1 in registers; u/v via redsum -> uu, sv   (K padded 36->40, KREAL=34)
  gemm_gw<64, 40, 34, 4, 1>(sh, sh.RA, 36, W1, b1, nullptr, 0, p1wl, p1wr, tid);
  __syncthreads();
  SCHED_FENCE();
  // score s[i] = sum_nbr u + bl + v[i]
  if (tid < 64) {
    unsigned long long m = sh.adjM[tid];
    float a = p1bl[0] + sh.sv[tid];
    #pragma unroll 1
    while (m) { int j = __builtin_ctzll(m); m &= m - 1; a += sh.uu[j]; }
    sh.sv[tid] = a;
  }
  __syncthreads();
  { // rank (RKP=4 lanes per row, 64 rows)
    int i = tid >> 2, p = tid & 3;
    float si = sh.sv[i];
    int cnt = 0;
    #pragma unroll
    for (int c = 0; c < 16; ++c) {
      int j = p * 16 + c;
      float sj = sh.sv[j];
      cnt += (sj > si || (sj == si && j < i)) ? 1 : 0;
    }
    cnt = redsum_i<4>(cnt);
    if (p == 0 && cnt < 32) { sh.sel[cnt] = i; sh.tv[cnt] = tanhf(si); }
  }
  __syncthreads();
  SCHED_FENCE();
  // snapshot old adjacency rows of selected; recompute x2 = relu(z1[sel].W1+b)*tv -> RB
  unsigned long long oldrow = 0ull;
  if (tid < 32) oldrow = sh.adjM[sh.sel[tid]];
  gemm_gw<32, 40, 34, 4, 2>(sh, sh.RA, 36, W1, b1, sh.RB, XLD, nullptr, nullptr, tid);
  __syncthreads();
  SCHED_FENCE();
  // filtered bitmask adjacency + next dinv; readout accumulate over x2
  if (tid < 32) {
    unsigned long long nm = 0ull;
    #pragma unroll 1
    for (int c = 0; c < 32; ++c)
      nm |= ((oldrow >> sh.sel[c]) & 1ull) << c;
    sh.adjM[tid] = nm;
    sh.dinv[tid] = rsqrtf(1.f + (float)__popcll(nm));
  }
  if (tid < H) {
    float m = -INFINITY, s = 0.f;
    #pragma unroll
    for (int r = 0; r < 32; ++r) {
      float v = sh.RB[r * XLD + tid];
      m = fmaxf(m, v); s += v;
    }
    rm += m;
    rs += s * (1.f / 32);
  }
  __syncthreads();
  SCHED_FENCE();

  // ---- stage 2: GCN(128->128) on 32 nodes, pool 32->16 ----
  norm_agg<32, 16, 8>(sh, sh.RB, XLD, sh.RA, XLD, tid);       // x2 -> z2
  __syncthreads();
  SCHED_FENCE();
  gemm_gw<32, 128, 128, 8, 0>(sh, sh.RA, XLD, W2, b2, sh.RB, XLD, nullptr, nullptr, tid); // z2 -> y2
  __syncthreads();
  SCHED_FENCE();
  sag_pool_readout<32, 16, 4, 8, true>(sh, sh.RB, sh.RA, p2wl, p2bl, p2wr, tid, rm, rs);  // y2 -> x3

  // ---- stage 3: GCN(128->128) on 16 nodes, pool 16->8 ----
  norm_agg<16, 16, 8>(sh, sh.RA, XLD, sh.RB, XLD, tid);       // x3 -> z3
  __syncthreads();
  SCHED_FENCE();
  gemm_gw<16, 128, 128, 8, 0>(sh, sh.RB, XLD, W3, b3, sh.RA, XLD, nullptr, nullptr, tid); // z3 -> y3
  __syncthreads();
  SCHED_FENCE();
  sag_pool_readout<16, 8, 8, 16, false>(sh, sh.RA, sh.RB, p3wl, p3bl, p3wr, tid, rm, rs); // y3 -> x4

  // ---- MLP head (scratch in RA: rbuf[0..256) | h1[256..384) | h1p[384..640) | h2p[640..896)) ----
  if (tid < H) { sh.RA[tid] = rm; sh.RA[H + tid] = rs; }
  __syncthreads();
  SCHED_FENCE();
  { // h1 partials: 128 f x 2 k-halves
    int f = tid & (H - 1), p = tid >> 7;
    const int base = p * 128;
    float a = 0.f;
    #pragma unroll 4
    for (int k = 0; k < 128; ++k) a += sh.RA[base + k] * mW1[(base + k) * H + f];
    sh.RA[384 + p * H + f] = a;
  }
  __syncthreads();
  SCHED_FENCE();
  if (tid < H) {
    float a = mb1[tid] + sh.RA[384 + tid] + sh.RA[384 + H + tid];
    sh.RA[256 + tid] = fmaxf(a, 0.f);
  }
  __syncthreads();
  SCHED_FENCE();
  { // h2 partials: 64 o x 4 k-parts
    int o = tid & 63, p = tid >> 6;
    const int base = p * 32;
    float a = 0.f;
    #pragma unroll 4
    for (int k = 0; k < 32; ++k) a += sh.RA[256 + base + k] * mW2[(base + k) * 64 + o];
    sh.RA[640 + p * 64 + o] = a;
  }
  __syncthreads();
  SCHED_FENCE();
  if (tid < 64) {
    float a = sh.RA[640 + tid] + sh.RA[704 + tid] + sh.RA[768 + tid] + sh.RA[832 + tid];
    a = fmaxf(a + mb2[tid], 0.f);
    float v = a * mW3[tid];
    v = redsum<64>(v);
    if (tid == 0) out[b] = v + mb3[0];
  }
}

extern "C" void kernel_launch(void* const* d_in, const int* in_sizes, int n_in,
                              void* d_out, int out_size, void* d_ws, size_t ws_size,
                              hipStream_t stream) {
  (void)n_in; (void)d_ws; (void)ws_size; (void)out_size;
  const int*   aa   = (const int*)  d_in[0];
  const float* pos  = (const float*)d_in[1];
  const float* cdr  = (const float*)d_in[2];
  const float* adj  = (const float*)d_in[3];
  const float* emb  = (const float*)d_in[4];
  const float* W1   = (const float*)d_in[5];
  const float* b1   = (const float*)d_in[6];
  const float* p1wl = (const float*)d_in[7];
  const float* p1bl = (const float*)d_in[8];
  const float* p1wr = (const float*)d_in[9];
  const float* W2   = (const float*)d_in[10];
  const float* b2   = (const float*)d_in[11];
  const float* p2wl = (const float*)d_in[12];
  const float* p2bl = (const float*)d_in[13];
  const float* p2wr = (const float*)d_in[14];
  const float* W3   = (const float*)d_in[15];
  const float* b3   = (const float*)d_in[16];
  const float* p3wl = (const float*)d_in[17];
  const float* p3bl = (const float*)d_in[18];
  const float* p3wr = (const float*)d_in[19];
  const float* mW1  = (const float*)d_in[20];
  const float* mb1  = (const float*)d_in[21];
  const float* mW2  = (const float*)d_in[22];
  const float* mb2  = (const float*)d_in[23];
  const float* mW3  = (const float*)d_in[24];
  const float* mb3  = (const float*)d_in[25];
  float* out = (float*)d_out;

  const int B = in_sizes[0] / N0;  // 4096
  hipLaunchKernelGGL(sagpool_fused, dim3(B), dim3(TPB), 0, stream,
                     aa, pos, cdr, adj, emb,
                     W1, b1, p1wl, p1bl, p1wr,
                     W2, b2, p2wl, p2bl, p2wr,
                     W3, b3, p3wl, p3bl, p3wr,
                     mW1, mb1, mW2, mb2, mW3, mb3, out);
}

// Round 13
// 272.055 us; speedup vs baseline: 2.2095x; 1.0457x over previous
//
#include <hip/hip_runtime.h>
#include <math.h>

#define TPB 256
static constexpr int N0 = 64;   // nodes per graph
static constexpr int H  = 128;  // hidden
static constexpr int LD = 132;  // stride of the stage-2/3 buffer (bank-skew + 16B aligned)

#define SCHED_FENCE() __builtin_amdgcn_sched_barrier(0)

// R11 arithmetic, in-place memory. One 32x132 buffer B serves x2->z2->y2->x3->z3->y3->x4
// (agg/gemm/gather all in place via reg staging + barrier). B2 holds xin/z1 [64][36]
// with adjM64/dinv64 in its tail (valid through stage 1 - no snapshot needed), and
// becomes MLP scratch afterwards. 28048 B -> 5 blocks/CU (20 waves).
struct alignas(16) Shm {
  float B[32 * LD];             // 16896 B
  float B2[2500];               // 10000 B: [0,2304) xin/z1; [2304,2308) zero pad;
                                //          [2308,2436) adjM64 (64 ull); [2436,2500) dinv64
  float uu[N0];                 // 256
  float sv[N0];                 // 256
  float tv[32];                 // 128
  float dinvS[32];              // 128
  unsigned long long adjS[32];  // 256
  int sel[32];                  // 128
};

template<int W>
__device__ __forceinline__ float redsum(float v) {
  #pragma unroll
  for (int m = W >> 1; m; m >>= 1) v += __shfl_xor(v, m, 64);
  return v;
}
template<int W>
__device__ __forceinline__ int redsum_i(int v) {
  #pragma unroll
  for (int m = W >> 1; m; m >>= 1) v += __shfl_xor(v, m, 64);
  return v;
}

// In-place normalized aggregation: buf = D^-1/2 (A+I) D^-1/2 buf.
// One (row, col-chunk) pair per thread; reads to regs, barrier, write back.
template<int NN, int GROUPS, int CPT, int STRIDE>
__device__ __forceinline__ void agg_inplace(float* buf,
    const unsigned long long* adj, const float* dinv, int tid) {
  float acc[CPT];
  const int i = tid & (NN - 1);
  const int g = tid / NN;
  const bool act = (g < GROUPS);
  if (act) {
    unsigned long long m = adj[i] | (1ull << i);  // A + I (diag of A is 0)
    #pragma unroll
    for (int c = 0; c < CPT; ++c) acc[c] = 0.f;
    const float* base = buf + g * CPT;
    #pragma unroll 1
    while (m) {
      int j = __builtin_ctzll(m); m &= m - 1;
      float a = dinv[j];
      const float* xp = base + j * STRIDE;
      #pragma unroll
      for (int c = 0; c < CPT; c += 4) {
        float4 xv = *(const float4*)(xp + c);
        acc[c]     += a * xv.x; acc[c + 1] += a * xv.y;
        acc[c + 2] += a * xv.z; acc[c + 3] += a * xv.w;
      }
    }
    float di = dinv[i];
    #pragma unroll
    for (int c = 0; c < CPT; ++c) acc[c] *= di;
  }
  __syncthreads();
  if (act) {
    float* op = buf + i * STRIDE + g * CPT;
    #pragma unroll
    for (int c = 0; c < CPT; c += 4)
      *(float4*)(op + c) = make_float4(acc[c], acc[c + 1], acc[c + 2], acc[c + 3]);
  }
  __syncthreads();
  SCHED_FENCE();
}

// GEMM, W streamed from global (register double-buffered KC-chunks).
// MODE 0: out[r][f] = relu(acc+b). INPLACE: barrier before epilogue (out may alias z).
// MODE 1: y in regs; u=y.wl, v=y.wr via redsum<64> -> uu, sv.
// MODE 2: rows gathered via sel; out[r][f] = relu(acc+b) * tv[r].
template<int R, int K, int KREAL, int KC, int MODE, bool INPLACE>
__device__ __forceinline__ void gemm_gw(Shm& sh, const float* z, int zld,
    const float* __restrict__ Wg, const float* __restrict__ bg,
    float* out, int old_,
    const float* __restrict__ wl, const float* __restrict__ wr, int tid) {
  constexpr int NR = R / 4;
  const int f  = tid & 63;
  const int r0 = (tid >> 6) * NR;
  float acc0[NR], acc1[NR];
  int zoff[NR];
  #pragma unroll
  for (int r = 0; r < NR; ++r) {
    acc0[r] = 0.f; acc1[r] = 0.f;
    int row = (MODE == 2) ? sh.sel[r0 + r] : (r0 + r);
    zoff[r] = row * zld;
  }
  float w0[KC], w1[KC], nw0[KC], nw1[KC];
  #pragma unroll
  for (int k = 0; k < KC; ++k) {
    w0[k] = (k < KREAL) ? Wg[k * H + f] : 0.f;
    w1[k] = (k < KREAL) ? Wg[k * H + f + 64] : 0.f;
  }
  #pragma unroll 1
  for (int kt = 0; kt < K; kt += KC) {
    if (kt + KC < K) {
      #pragma unroll
      for (int k = 0; k < KC; ++k) {
        int gr = kt + KC + k;
        nw0[k] = (gr < KREAL) ? Wg[gr * H + f] : 0.f;
        nw1[k] = (gr < KREAL) ? Wg[gr * H + f + 64] : 0.f;
      }
    }
    #pragma unroll
    for (int r = 0; r < NR; ++r) {
      const float* zr = z + zoff[r] + kt;
      #pragma unroll
      for (int k = 0; k < KC; k += 4) {
        float4 zv = *(const float4*)(zr + k);
        acc0[r] += zv.x * w0[k] + zv.y * w0[k + 1] + zv.z * w0[k + 2] + zv.w * w0[k + 3];
        acc1[r] += zv.x * w1[k] + zv.y * w1[k + 1] + zv.z * w1[k + 2] + zv.w * w1[k + 3];
      }
    }
    #pragma unroll
    for (int k = 0; k < KC; ++k) { w0[k] = nw0[k]; w1[k] = nw1[k]; }
  }
  const float b0 = bg[f], b1 = bg[f + 64];
  if constexpr (MODE == 1) {
    const float wl0 = wl[f], wl1 = wl[f + 64];
    const float wr0 = wr[f], wr1 = wr[f + 64];
    #pragma unroll
    for (int r = 0; r < NR; ++r) {
      float y0 = fmaxf(acc0[r] + b0, 0.f);
      float y1 = fmaxf(acc1[r] + b1, 0.f);
      float up = y0 * wl0 + y1 * wl1;
      float vp = y0 * wr0 + y1 * wr1;
      up = redsum<64>(up);
      vp = redsum<64>(vp);
      if (f == 0) { sh.uu[r0 + r] = up; sh.sv[r0 + r] = vp; }
    }
  } else {
    if constexpr (INPLACE) __syncthreads();  // all z reads done before y overwrite
    #pragma unroll
    for (int r = 0; r < NR; ++r) {
      float t = (MODE == 2) ? sh.tv[r0 + r] : 1.f;
      out[(r0 + r) * old_ + f]      = fmaxf(acc0[r] + b0, 0.f) * t;
      out[(r0 + r) * old_ + f + 64] = fmaxf(acc1[r] + b1, 0.f) * t;
    }
  }
}

// s[i] = sum_{j in nbr(i)} u[j] + bl + v[i]   (v already in sv[i])
template<int NN>
__device__ __forceinline__ void score(const unsigned long long* adj, Shm& sh,
                                      float bl, int tid) {
  if (tid < NN) {
    unsigned long long m = adj[tid];
    float a = bl + sh.sv[tid];
    #pragma unroll 1
    while (m) { int j = __builtin_ctzll(m); m &= m - 1; a += sh.uu[j]; }
    sh.sv[tid] = a;
  }
}

// exact stable top-k via parallel rank counting (NN*RKP == TPB)
template<int NN, int KK, int RKP>
__device__ __forceinline__ void rank_topk(Shm& sh, int tid) {
  int i = tid / RKP, p = tid % RKP;
  constexpr int CHr = NN / RKP;
  float si = sh.sv[i];
  int cnt = 0;
  #pragma unroll
  for (int c = 0; c < CHr; ++c) {
    int j = p * CHr + c;
    float sj = sh.sv[j];
    cnt += (sj > si || (sj == si && j < i)) ? 1 : 0;
  }
  cnt = redsum_i<RKP>(cnt);
  if (p == 0 && cnt < KK) { sh.sel[cnt] = i; sh.tv[cnt] = tanhf(si); }
}

// readout accumulate over KK rows of xn (stride ld)
template<int KK>
__device__ __forceinline__ void readout(const float* xn, int ld, int tid,
                                        float& rm, float& rs) {
  if (tid < H) {
    float m = -INFINITY, s = 0.f;
    #pragma unroll
    for (int r = 0; r < KK; ++r) {
      float v = xn[r * ld + tid];
      m = fmaxf(m, v); s += v;
    }
    rm += m;
    rs += s * (1.f / KK);
  }
}

// SAGPool for stages 2/3, fully IN PLACE on x (= y, stride LD):
// u/v (R11 order) -> score -> rank -> reg-staged in-place gather -> filter -> readout.
template<int NN, int KK, int UVP, int RKP, bool DOFILT>
__device__ __forceinline__ void sag_pool_inplace(Shm& sh, float* x,
    const float* __restrict__ wl, const float* __restrict__ blp,
    const float* __restrict__ wr, int tid, float& rm, float& rs) {
  { // u[j]=y[j].wl -> uu, v[j]=y[j].wr -> sv  (2*NN*UVP == TPB)
    int dot = tid / UVP, p = tid % UVP;
    int j = dot >> 1;
    const float* wp = (dot & 1) ? wr : wl;
    constexpr int CH = H / UVP;
    const float* xr = x + j * LD + p * CH;
    const float* wq = wp + p * CH;
    float a = 0.f;
    #pragma unroll
    for (int k = 0; k < CH; k += 4) {
      float4 xv = *(const float4*)(xr + k);
      float4 wv = *(const float4*)(wq + k);
      a += xv.x * wv.x + xv.y * wv.y + xv.z * wv.z + xv.w * wv.w;
    }
    a = redsum<UVP>(a);
    if (p == 0) { if (dot & 1) sh.sv[j] = a; else sh.uu[j] = a; }
  }
  __syncthreads();
  SCHED_FENCE();
  score<NN>(sh.adjS, sh, blp[0], tid);
  __syncthreads();
  rank_topk<NN, KK, RKP>(sh, tid);
  __syncthreads();
  SCHED_FENCE();
  // snapshot old rows; reg-staged in-place gather x[r] = y[sel[r]] * tv[r]
  unsigned long long oldrow = 0ull;
  if (tid < KK) oldrow = sh.adjS[sh.sel[tid]];
  constexpr int NV  = KK * (H / 4);
  constexpr int PER = (NV + TPB - 1) / TPB;
  float4 stg[PER]; int dst[PER];
  #pragma unroll
  for (int q = 0; q < PER; ++q) {
    int e = tid + q * TPB;
    if (e < NV) {
      int r = e / (H / 4), c = (e % (H / 4)) * 4;
      float4 v = *(const float4*)(x + sh.sel[r] * LD + c);
      float t = sh.tv[r];
      stg[q] = make_float4(v.x * t, v.y * t, v.z * t, v.w * t);
      dst[q] = r * LD + c;
    }
  }
  __syncthreads();
  #pragma unroll
  for (int q = 0; q < PER; ++q) {
    int e = tid + q * TPB;
    if (e < NV) *(float4*)(x + dst[q]) = stg[q];
  }
  __syncthreads();
  SCHED_FENCE();
  if (DOFILT && tid < KK) {
    unsigned long long nm = 0ull;
    #pragma unroll 1
    for (int c = 0; c < KK; ++c)
      nm |= ((oldrow >> sh.sel[c]) & 1ull) << c;
    sh.adjS[tid] = nm;
    sh.dinvS[tid] = rsqrtf(1.f + (float)__popcll(nm));
  }
  readout<KK>(x, LD, tid, rm, rs);
  __syncthreads();
  SCHED_FENCE();
}

__global__ __launch_bounds__(TPB, 5) void sagpool_fused(
    const int* __restrict__ aa, const float* __restrict__ pos,
    const float* __restrict__ cdr, const float* __restrict__ adjG,
    const float* __restrict__ emb,
    const float* __restrict__ W1, const float* __restrict__ b1,
    const float* __restrict__ p1wl, const float* __restrict__ p1bl, const float* __restrict__ p1wr,
    const float* __restrict__ W2, const float* __restrict__ b2,
    const float* __restrict__ p2wl, const float* __restrict__ p2bl, const float* __restrict__ p2wr,
    const float* __restrict__ W3, const float* __restrict__ b3,
    const float* __restrict__ p3wl, const float* __restrict__ p3bl, const float* __restrict__ p3wr,
    const float* __restrict__ mW1, const float* __restrict__ mb1,
    const float* __restrict__ mW2, const float* __restrict__ mb2,
    const float* __restrict__ mW3, const float* __restrict__ mb3,
    float* __restrict__ out)
{
  __shared__ Shm sh;
  const int b   = blockIdx.x;
  const int tid = threadIdx.x;

  unsigned long long* adjM64 = (unsigned long long*)(sh.B2 + 2308);
  float* dinv64 = sh.B2 + 2436;

  float rm = 0.f, rs = 0.f;   // readout accumulators (feature = tid, tid < 128)

  // adjacency [64][64] -> 64-bit row masks + fused degree/dinv (4 lanes/row)
  {
    const float* rp = adjG + (size_t)b * (N0 * N0) + (tid >> 2) * N0 + (tid & 3) * 16;
    unsigned long long mpart = 0ull;
    #pragma unroll
    for (int q = 0; q < 16; q += 4) {
      float4 v = *(const float4*)(rp + q);
      unsigned int bits = (v.x != 0.f ? 1u : 0u) | (v.y != 0.f ? 2u : 0u)
                        | (v.z != 0.f ? 4u : 0u) | (v.w != 0.f ? 8u : 0u);
      mpart |= (unsigned long long)bits << q;
    }
    mpart <<= ((tid & 3) * 16);
    mpart |= __shfl_xor(mpart, 1, 64);
    mpart |= __shfl_xor(mpart, 2, 64);
    if ((tid & 3) == 0) {
      int r = tid >> 2;
      adjM64[r] = mpart;
      dinv64[r] = rsqrtf(1.f + (float)__popcll(mpart));
    }
  }
  if (tid < 4) sh.B2[2304 + tid] = 0.f;   // zero the K=40 overread pad
  SCHED_FENCE();
  // build xin = [emb[aa] | pos | is_cdr3 | 0 0] -> B2 [64][36]
  #pragma unroll 1
  for (int e = tid; e < N0 * 36; e += TPB) {
    int j = e / 36, k = e - j * 36;
    int node = b * N0 + j;
    float v;
    if (k < 32)       v = emb[aa[node] * 32 + k];
    else if (k == 32) v = pos[node];
    else if (k == 33) v = cdr[node];
    else              v = 0.f;
    sh.B2[e] = v;
  }
  __syncthreads();
  SCHED_FENCE();

  // ---- stage 1: GCN(34->128) on 64 nodes, pool 64->32 (y1 never stored) ----
  agg_inplace<64, 3, 12, 36>(sh.B2, adjM64, dinv64, tid);     // xin -> z1 in place
  gemm_gw<64, 40, 34, 4, 1, false>(sh, sh.B2, 36, W1, b1, nullptr, 0, p1wl, p1wr, tid);
  __syncthreads();
  SCHED_FENCE();
  score<64>(adjM64, sh, p1bl[0], tid);
  __syncthreads();
  rank_topk<64, 32, 4>(sh, tid);
  __syncthreads();
  SCHED_FENCE();
  gemm_gw<32, 40, 34, 4, 2, false>(sh, sh.B2, 36, W1, b1, sh.B, LD, nullptr, nullptr, tid); // x2 -> B
  __syncthreads();
  SCHED_FENCE();
  if (tid < 32) {   // adjM64 still valid (B2 tail untouched)
    unsigned long long oldrow = adjM64[sh.sel[tid]];
    unsigned long long nm = 0ull;
    #pragma unroll 1
    for (int c = 0; c < 32; ++c)
      nm |= ((oldrow >> sh.sel[c]) & 1ull) << c;
    sh.adjS[tid] = nm;
    sh.dinvS[tid] = rsqrtf(1.f + (float)__popcll(nm));
  }
  readout<32>(sh.B, LD, tid, rm, rs);
  __syncthreads();
  SCHED_FENCE();

  // ---- stage 2: GCN(128->128) on 32 nodes, pool 32->16 ----
  agg_inplace<32, 8, 16, LD>(sh.B, sh.adjS, sh.dinvS, tid);   // x2 -> z2 in place
  gemm_gw<32, 128, 128, 8, 0, true>(sh, sh.B, LD, W2, b2, sh.B, LD, nullptr, nullptr, tid); // y2 in place
  __syncthreads();
  SCHED_FENCE();
  sag_pool_inplace<32, 16, 4, 8, true>(sh, sh.B, p2wl, p2bl, p2wr, tid, rm, rs);  // x3 rows 0..15

  // ---- stage 3: GCN(128->128) on 16 nodes, pool 16->8 ----
  agg_inplace<16, 16, 8, LD>(sh.B, sh.adjS, sh.dinvS, tid);   // x3 -> z3 in place
  gemm_gw<16, 128, 128, 8, 0, true>(sh, sh.B, LD, W3, b3, sh.B, LD, nullptr, nullptr, tid); // y3 in place
  __syncthreads();
  SCHED_FENCE();
  sag_pool_inplace<16, 8, 8, 16, false>(sh, sh.B, p3wl, p3bl, p3wr, tid, rm, rs); // x4 rows 0..7 + readout

  // ---- MLP head (B2 is dead: scratch rbuf[0..256) | h1[256..384) | h1p[384..640) | h2p[640..896)) ----
  if (tid < H) { sh.B2[tid] = rm; sh.B2[H + tid] = rs; }
  __syncthreads();
  SCHED_FENCE();
  { // h1 partials: 128 f x 2 k-halves
    int f = tid & (H - 1), p = tid >> 7;
    const int base = p * 128;
    float a = 0.f;
    #pragma unroll 4
    for (int k = 0; k < 128; ++k) a += sh.B2[base + k] * mW1[(base + k) * H + f];
    sh.B2[384 + p * H + f] = a;
  }
  __syncthreads();
  SCHED_FENCE();
  if (tid < H) {
    float a = mb1[tid] + sh.B2[384 + tid] + sh.B2[384 + H + tid];
    sh.B2[256 + tid] = fmaxf(a, 0.f);
  }
  __syncthreads();
  SCHED_FENCE();
  { // h2 partials: 64 o x 4 k-parts
    int o = tid & 63, p = tid >> 6;
    const int base = p * 32;
    float a = 0.f;
    #pragma unroll 4
    for (int k = 0; k < 32; ++k) a += sh.B2[256 + base + k] * mW2[(base + k) * 64 + o];
    sh.B2[640 + p * 64 + o] = a;
  }
  __syncthreads();
  SCHED_FENCE();
  if (tid < 64) {
    float a = sh.B2[640 + tid] + sh.B2[704 + tid] + sh.B2[768 + tid] + sh.B2[832 + tid];
    a = fmaxf(a + mb2[tid], 0.f);
    float v = a * mW3[tid];
    v = redsum<64>(v);
    if (tid == 0) out[b] = v + mb3[0];
  }
}

extern "C" void kernel_launch(void* const* d_in, const int* in_sizes, int n_in,
                              void* d_out, int out_size, void* d_ws, size_t ws_size,
                              hipStream_t stream) {
  (void)n_in; (void)d_ws; (void)ws_size; (void)out_size;
  const int*   aa   = (const int*)  d_in[0];
  const float* pos  = (const float*)d_in[1];
  const float* cdr  = (const float*)d_in[2];
  const float* adj  = (const float*)d_in[3];
  const float* emb  = (const float*)d_in[4];
  const float* W1   = (const float*)d_in[5];
  const float* b1   = (const float*)d_in[6];
  const float* p1wl = (const float*)d_in[7];
  const float* p1bl = (const float*)d_in[8];
  const float* p1wr = (const float*)d_in[9];
  const float* W2   = (const float*)d_in[10];
  const float* b2   = (const float*)d_in[11];
  const float* p2wl = (const float*)d_in[12];
  const float* p2bl = (const float*)d_in[13];
  const float* p2wr = (const float*)d_in[14];
  const float* W3   = (const float*)d_in[15];
  const float* b3   = (const float*)d_in[16];
  const float* p3wl = (const float*)d_in[17];
  const float* p3bl = (const float*)d_in[18];
  const float* p3wr = (const float*)d_in[19];
  const float* mW1  = (const float*)d_in[20];
  const float* mb1  = (const float*)d_in[21];
  const float* mW2  = (const float*)d_in[22];
  const float* mb2  = (const float*)d_in[23];
  const float* mW3  = (const float*)d_in[24];
  const float* mb3  = (const float*)d_in[25];
  float* out = (float*)d_out;

  const int B = in_sizes[0] / N0;  // 4096
  hipLaunchKernelGGL(sagpool_fused, dim3(B), dim3(TPB), 0, stream,
                     aa, pos, cdr, adj, emb,
                     W1, b1, p1wl, p1bl, p1wr,
                     W2, b2, p2wl, p2bl, p2wr,
                     W3, b3, p3wl, p3bl, p3wr,
                     mW1, mb1, mW2, mb2, mW3, mb3, out);
}

// Round 14
// 261.201 us; speedup vs baseline: 2.3013x; 1.0416x over previous
//
#include <hip/hip_runtime.h>
#include <math.h>

#define TPB 256
static constexpr int N0 = 64;   // nodes per graph
static constexpr int H  = 128;  // hidden
static constexpr int LD = 132;  // stride of the stage-2/3 buffer (bank-skew + 16B aligned)

#define SCHED_FENCE() __builtin_amdgcn_sched_barrier(0)

// R13 layout (28048 B -> 5 blocks/CU), gemm re-threaded: 32 col-groups x 8
// row-groups, float4 W loads (half the W-load instrs), redsum<32> for u/v.
struct alignas(16) Shm {
  float B[32 * LD];             // 16896 B
  float B2[2500];               // 10000 B: [0,2304) xin/z1; [2304,2308) zero pad;
                                //          [2308,2436) adjM64 (64 ull); [2436,2500) dinv64
  float uu[N0];                 // 256
  float sv[N0];                 // 256
  float tv[32];                 // 128
  float dinvS[32];              // 128
  unsigned long long adjS[32];  // 256
  int sel[32];                  // 128
};

template<int W>
__device__ __forceinline__ float redsum(float v) {
  #pragma unroll
  for (int m = W >> 1; m; m >>= 1) v += __shfl_xor(v, m, 64);
  return v;
}
template<int W>
__device__ __forceinline__ int redsum_i(int v) {
  #pragma unroll
  for (int m = W >> 1; m; m >>= 1) v += __shfl_xor(v, m, 64);
  return v;
}

// In-place normalized aggregation: buf = D^-1/2 (A+I) D^-1/2 buf.
template<int NN, int GROUPS, int CPT, int STRIDE>
__device__ __forceinline__ void agg_inplace(float* buf,
    const unsigned long long* adj, const float* dinv, int tid) {
  float acc[CPT];
  const int i = tid & (NN - 1);
  const int g = tid / NN;
  const bool act = (g < GROUPS);
  if (act) {
    unsigned long long m = adj[i] | (1ull << i);  // A + I (diag of A is 0)
    #pragma unroll
    for (int c = 0; c < CPT; ++c) acc[c] = 0.f;
    const float* base = buf + g * CPT;
    #pragma unroll 1
    while (m) {
      int j = __builtin_ctzll(m); m &= m - 1;
      float a = dinv[j];
      const float* xp = base + j * STRIDE;
      #pragma unroll
      for (int c = 0; c < CPT; c += 4) {
        float4 xv = *(const float4*)(xp + c);
        acc[c]     += a * xv.x; acc[c + 1] += a * xv.y;
        acc[c + 2] += a * xv.z; acc[c + 3] += a * xv.w;
      }
    }
    float di = dinv[i];
    #pragma unroll
    for (int c = 0; c < CPT; ++c) acc[c] *= di;
  }
  __syncthreads();
  if (act) {
    float* op = buf + i * STRIDE + g * CPT;
    #pragma unroll
    for (int c = 0; c < CPT; c += 4)
      *(float4*)(op + c) = make_float4(acc[c], acc[c + 1], acc[c + 2], acc[c + 3]);
  }
  __syncthreads();
  SCHED_FENCE();
}

// GEMM, W streamed from global in float4 (4 cols/thread), reg double-buffered.
// Threads: fc = (tid&31)*4 (cols fc..fc+3), r0 = (tid>>5)*NR, NR = R/8.
// MODE 0: out[r][fc..] = relu(acc+b). INPLACE: barrier before epilogue.
// MODE 1: y in regs; u=y.wl, v=y.wr via redsum<32> -> uu, sv.
// MODE 2: rows gathered via sel; out[r][fc..] = relu(acc+b) * tv[r].
template<int R, int K, int KREAL, int MODE, bool INPLACE>
__device__ __forceinline__ void gemm_gw(Shm& sh, const float* z, int zld,
    const float* __restrict__ Wg, const float* __restrict__ bg,
    float* out, int old_,
    const float* __restrict__ wl, const float* __restrict__ wr, int tid) {
  constexpr int NR = R / 8;
  constexpr int KC = 4;
  const int fc = (tid & 31) * 4;
  const int r0 = (tid >> 5) * NR;
  float4 acc[NR];
  int zoff[NR];
  #pragma unroll
  for (int r = 0; r < NR; ++r) {
    acc[r] = make_float4(0.f, 0.f, 0.f, 0.f);
    int row = (MODE == 2) ? sh.sel[r0 + r] : (r0 + r);
    zoff[r] = row * zld;
  }
  float4 w[KC], nw[KC];
  #pragma unroll
  for (int k = 0; k < KC; ++k)
    w[k] = (k < KREAL) ? *(const float4*)(Wg + k * H + fc)
                       : make_float4(0.f, 0.f, 0.f, 0.f);
  #pragma unroll 1
  for (int kt = 0; kt < K; kt += KC) {
    if (kt + KC < K) {
      #pragma unroll
      for (int k = 0; k < KC; ++k) {
        int gr = kt + KC + k;
        nw[k] = (gr < KREAL) ? *(const float4*)(Wg + gr * H + fc)
                             : make_float4(0.f, 0.f, 0.f, 0.f);
      }
    }
    #pragma unroll
    for (int r = 0; r < NR; ++r) {
      float4 zv = *(const float4*)(z + zoff[r] + kt);
      acc[r].x += zv.x * w[0].x + zv.y * w[1].x + zv.z * w[2].x + zv.w * w[3].x;
      acc[r].y += zv.x * w[0].y + zv.y * w[1].y + zv.z * w[2].y + zv.w * w[3].y;
      acc[r].z += zv.x * w[0].z + zv.y * w[1].z + zv.z * w[2].z + zv.w * w[3].z;
      acc[r].w += zv.x * w[0].w + zv.y * w[1].w + zv.z * w[2].w + zv.w * w[3].w;
    }
    #pragma unroll
    for (int k = 0; k < KC; ++k) w[k] = nw[k];
  }
  const float4 b4 = *(const float4*)(bg + fc);
  if constexpr (MODE == 1) {
    const float4 wl4 = *(const float4*)(wl + fc);
    const float4 wr4 = *(const float4*)(wr + fc);
    #pragma unroll
    for (int r = 0; r < NR; ++r) {
      float y0 = fmaxf(acc[r].x + b4.x, 0.f);
      float y1 = fmaxf(acc[r].y + b4.y, 0.f);
      float y2 = fmaxf(acc[r].z + b4.z, 0.f);
      float y3 = fmaxf(acc[r].w + b4.w, 0.f);
      float up = y0 * wl4.x + y1 * wl4.y + y2 * wl4.z + y3 * wl4.w;
      float vp = y0 * wr4.x + y1 * wr4.y + y2 * wr4.z + y3 * wr4.w;
      up = redsum<32>(up);
      vp = redsum<32>(vp);
      if ((tid & 31) == 0) { sh.uu[r0 + r] = up; sh.sv[r0 + r] = vp; }
    }
  } else {
    if constexpr (INPLACE) __syncthreads();  // all z reads done before overwrite
    #pragma unroll
    for (int r = 0; r < NR; ++r) {
      float t = (MODE == 2) ? sh.tv[r0 + r] : 1.f;
      float4 o;
      o.x = fmaxf(acc[r].x + b4.x, 0.f) * t;
      o.y = fmaxf(acc[r].y + b4.y, 0.f) * t;
      o.z = fmaxf(acc[r].z + b4.z, 0.f) * t;
      o.w = fmaxf(acc[r].w + b4.w, 0.f) * t;
      *(float4*)(out + (r0 + r) * old_ + fc) = o;
    }
  }
}

// s[i] = sum_{j in nbr(i)} u[j] + bl + v[i]   (v already in sv[i])
template<int NN>
__device__ __forceinline__ void score(const unsigned long long* adj, Shm& sh,
                                      float bl, int tid) {
  if (tid < NN) {
    unsigned long long m = adj[tid];
    float a = bl + sh.sv[tid];
    #pragma unroll 1
    while (m) { int j = __builtin_ctzll(m); m &= m - 1; a += sh.uu[j]; }
    sh.sv[tid] = a;
  }
}

// exact stable top-k via parallel rank counting (NN*RKP == TPB)
template<int NN, int KK, int RKP>
__device__ __forceinline__ void rank_topk(Shm& sh, int tid) {
  int i = tid / RKP, p = tid % RKP;
  constexpr int CHr = NN / RKP;
  float si = sh.sv[i];
  int cnt = 0;
  #pragma unroll
  for (int c = 0; c < CHr; ++c) {
    int j = p * CHr + c;
    float sj = sh.sv[j];
    cnt += (sj > si || (sj == si && j < i)) ? 1 : 0;
  }
  cnt = redsum_i<RKP>(cnt);
  if (p == 0 && cnt < KK) { sh.sel[cnt] = i; sh.tv[cnt] = tanhf(si); }
}

// readout accumulate over KK rows of xn (stride ld)
template<int KK>
__device__ __forceinline__ void readout(const float* xn, int ld, int tid,
                                        float& rm, float& rs) {
  if (tid < H) {
    float m = -INFINITY, s = 0.f;
    #pragma unroll
    for (int r = 0; r < KK; ++r) {
      float v = xn[r * ld + tid];
      m = fmaxf(m, v); s += v;
    }
    rm += m;
    rs += s * (1.f / KK);
  }
}

// SAGPool for stages 2/3, fully IN PLACE on x (= y, stride LD).
template<int NN, int KK, int UVP, int RKP, bool DOFILT>
__device__ __forceinline__ void sag_pool_inplace(Shm& sh, float* x,
    const float* __restrict__ wl, const float* __restrict__ blp,
    const float* __restrict__ wr, int tid, float& rm, float& rs) {
  { // u[j]=y[j].wl -> uu, v[j]=y[j].wr -> sv  (2*NN*UVP == TPB)
    int dot = tid / UVP, p = tid % UVP;
    int j = dot >> 1;
    const float* wp = (dot & 1) ? wr : wl;
    constexpr int CH = H / UVP;
    const float* xr = x + j * LD + p * CH;
    const float* wq = wp + p * CH;
    float a = 0.f;
    #pragma unroll
    for (int k = 0; k < CH; k += 4) {
      float4 xv = *(const float4*)(xr + k);
      float4 wv = *(const float4*)(wq + k);
      a += xv.x * wv.x + xv.y * wv.y + xv.z * wv.z + xv.w * wv.w;
    }
    a = redsum<UVP>(a);
    if (p == 0) { if (dot & 1) sh.sv[j] = a; else sh.uu[j] = a; }
  }
  __syncthreads();
  SCHED_FENCE();
  score<NN>(sh.adjS, sh, blp[0], tid);
  __syncthreads();
  rank_topk<NN, KK, RKP>(sh, tid);
  __syncthreads();
  SCHED_FENCE();
  // snapshot old rows; reg-staged in-place gather x[r] = y[sel[r]] * tv[r]
  unsigned long long oldrow = 0ull;
  if (tid < KK) oldrow = sh.adjS[sh.sel[tid]];
  constexpr int NV  = KK * (H / 4);
  constexpr int PER = (NV + TPB - 1) / TPB;
  float4 stg[PER]; int dst[PER];
  #pragma unroll
  for (int q = 0; q < PER; ++q) {
    int e = tid + q * TPB;
    if (e < NV) {
      int r = e / (H / 4), c = (e % (H / 4)) * 4;
      float4 v = *(const float4*)(x + sh.sel[r] * LD + c);
      float t = sh.tv[r];
      stg[q] = make_float4(v.x * t, v.y * t, v.z * t, v.w * t);
      dst[q] = r * LD + c;
    }
  }
  __syncthreads();
  #pragma unroll
  for (int q = 0; q < PER; ++q) {
    int e = tid + q * TPB;
    if (e < NV) *(float4*)(x + dst[q]) = stg[q];
  }
  __syncthreads();
  SCHED_FENCE();
  if (DOFILT && tid < KK) {
    unsigned long long nm = 0ull;
    #pragma unroll 1
    for (int c = 0; c < KK; ++c)
      nm |= ((oldrow >> sh.sel[c]) & 1ull) << c;
    sh.adjS[tid] = nm;
    sh.dinvS[tid] = rsqrtf(1.f + (float)__popcll(nm));
  }
  readout<KK>(x, LD, tid, rm, rs);
  __syncthreads();
  SCHED_FENCE();
}

__global__ __launch_bounds__(TPB, 5) void sagpool_fused(
    const int* __restrict__ aa, const float* __restrict__ pos,
    const float* __restrict__ cdr, const float* __restrict__ adjG,
    const float* __restrict__ emb,
    const float* __restrict__ W1, const float* __restrict__ b1,
    const float* __restrict__ p1wl, const float* __restrict__ p1bl, const float* __restrict__ p1wr,
    const float* __restrict__ W2, const float* __restrict__ b2,
    const float* __restrict__ p2wl, const float* __restrict__ p2bl, const float* __restrict__ p2wr,
    const float* __restrict__ W3, const float* __restrict__ b3,
    const float* __restrict__ p3wl, const float* __restrict__ p3bl, const float* __restrict__ p3wr,
    const float* __restrict__ mW1, const float* __restrict__ mb1,
    const float* __restrict__ mW2, const float* __restrict__ mb2,
    const float* __restrict__ mW3, const float* __restrict__ mb3,
    float* __restrict__ out)
{
  __shared__ Shm sh;
  const int b   = blockIdx.x;
  const int tid = threadIdx.x;

  unsigned long long* adjM64 = (unsigned long long*)(sh.B2 + 2308);
  float* dinv64 = sh.B2 + 2436;

  float rm = 0.f, rs = 0.f;   // readout accumulators (feature = tid, tid < 128)

  // adjacency [64][64] -> 64-bit row masks + fused degree/dinv (4 lanes/row)
  {
    const float* rp = adjG + (size_t)b * (N0 * N0) + (tid >> 2) * N0 + (tid & 3) * 16;
    unsigned long long mpart = 0ull;
    #pragma unroll
    for (int q = 0; q < 16; q += 4) {
      float4 v = *(const float4*)(rp + q);
      unsigned int bits = (v.x != 0.f ? 1u : 0u) | (v.y != 0.f ? 2u : 0u)
                        | (v.z != 0.f ? 4u : 0u) | (v.w != 0.f ? 8u : 0u);
      mpart |= (unsigned long long)bits << q;
    }
    mpart <<= ((tid & 3) * 16);
    mpart |= __shfl_xor(mpart, 1, 64);
    mpart |= __shfl_xor(mpart, 2, 64);
    if ((tid & 3) == 0) {
      int r = tid >> 2;
      adjM64[r] = mpart;
      dinv64[r] = rsqrtf(1.f + (float)__popcll(mpart));
    }
  }
  if (tid < 4) sh.B2[2304 + tid] = 0.f;   // zero the overread pad
  SCHED_FENCE();
  // build xin = [emb[aa] | pos | is_cdr3 | 0 0] -> B2 [64][36]
  #pragma unroll 1
  for (int e = tid; e < N0 * 36; e += TPB) {
    int j = e / 36, k = e - j * 36;
    int node = b * N0 + j;
    float v;
    if (k < 32)       v = emb[aa[node] * 32 + k];
    else if (k == 32) v = pos[node];
    else if (k == 33) v = cdr[node];
    else              v = 0.f;
    sh.B2[e] = v;
  }
  __syncthreads();
  SCHED_FENCE();

  // ---- stage 1: GCN(34->128) on 64 nodes, pool 64->32 (y1 never stored) ----
  agg_inplace<64, 3, 12, 36>(sh.B2, adjM64, dinv64, tid);     // xin -> z1 in place
  gemm_gw<64, 36, 34, 1, false>(sh, sh.B2, 36, W1, b1, nullptr, 0, p1wl, p1wr, tid);
  __syncthreads();
  SCHED_FENCE();
  score<64>(adjM64, sh, p1bl[0], tid);
  __syncthreads();
  rank_topk<64, 32, 4>(sh, tid);
  __syncthreads();
  SCHED_FENCE();
  gemm_gw<32, 36, 34, 2, false>(sh, sh.B2, 36, W1, b1, sh.B, LD, nullptr, nullptr, tid); // x2 -> B
  __syncthreads();
  SCHED_FENCE();
  if (tid < 32) {   // adjM64 still valid (B2 tail untouched)
    unsigned long long oldrow = adjM64[sh.sel[tid]];
    unsigned long long nm = 0ull;
    #pragma unroll 1
    for (int c = 0; c < 32; ++c)
      nm |= ((oldrow >> sh.sel[c]) & 1ull) << c;
    sh.adjS[tid] = nm;
    sh.dinvS[tid] = rsqrtf(1.f + (float)__popcll(nm));
  }
  readout<32>(sh.B, LD, tid, rm, rs);
  __syncthreads();
  SCHED_FENCE();

  // ---- stage 2: GCN(128->128) on 32 nodes, pool 32->16 ----
  agg_inplace<32, 8, 16, LD>(sh.B, sh.adjS, sh.dinvS, tid);   // x2 -> z2 in place
  gemm_gw<32, 128, 128, 0, true>(sh, sh.B, LD, W2, b2, sh.B, LD, nullptr, nullptr, tid); // y2 in place
  __syncthreads();
  SCHED_FENCE();
  sag_pool_inplace<32, 16, 4, 8, true>(sh, sh.B, p2wl, p2bl, p2wr, tid, rm, rs);  // x3 rows 0..15

  // ---- stage 3: GCN(128->128) on 16 nodes, pool 16->8 ----
  agg_inplace<16, 16, 8, LD>(sh.B, sh.adjS, sh.dinvS, tid);   // x3 -> z3 in place
  gemm_gw<16, 128, 128, 0, true>(sh, sh.B, LD, W3, b3, sh.B, LD, nullptr, nullptr, tid); // y3 in place
  __syncthreads();
  SCHED_FENCE();
  sag_pool_inplace<16, 8, 8, 16, false>(sh, sh.B, p3wl, p3bl, p3wr, tid, rm, rs); // x4 rows 0..7

  // ---- MLP head (B2 dead: rbuf[0..256) | h1[256..384) | h1p[384..640) | h2p[640..896)) ----
  if (tid < H) { sh.B2[tid] = rm; sh.B2[H + tid] = rs; }
  __syncthreads();
  SCHED_FENCE();
  { // h1 partials: 128 f x 2 k-halves
    int f = tid & (H - 1), p = tid >> 7;
    const int base = p * 128;
    float a = 0.f;
    #pragma unroll 4
    for (int k = 0; k < 128; ++k) a += sh.B2[base + k] * mW1[(base + k) * H + f];
    sh.B2[384 + p * H + f] = a;
  }
  __syncthreads();
  SCHED_FENCE();
  if (tid < H) {
    float a = mb1[tid] + sh.B2[384 + tid] + sh.B2[384 + H + tid];
    sh.B2[256 + tid] = fmaxf(a, 0.f);
  }
  __syncthreads();
  SCHED_FENCE();
  { // h2 partials: 64 o x 4 k-parts
    int o = tid & 63, p = tid >> 6;
    const int base = p * 32;
    float a = 0.f;
    #pragma unroll 4
    for (int k = 0; k < 32; ++k) a += sh.B2[256 + base + k] * mW2[(base + k) * 64 + o];
    sh.B2[640 + p * 64 + o] = a;
  }
  __syncthreads();
  SCHED_FENCE();
  if (tid < 64) {
    float a = sh.B2[640 + tid] + sh.B2[704 + tid] + sh.B2[768 + tid] + sh.B2[832 + tid];
    a = fmaxf(a + mb2[tid], 0.f);
    float v = a * mW3[tid];
    v = redsum<64>(v);
    if (tid == 0) out[b] = v + mb3[0];
  }
}

extern "C" void kernel_launch(void* const* d_in, const int* in_sizes, int n_in,
                              void* d_out, int out_size, void* d_ws, size_t ws_size,
                              hipStream_t stream) {
  (void)n_in; (void)d_ws; (void)ws_size; (void)out_size;
  const int*   aa   = (const int*)  d_in[0];
  const float* pos  = (const float*)d_in[1];
  const float* cdr  = (const float*)d_in[2];
  const float* adj  = (const float*)d_in[3];
  const float* emb  = (const float*)d_in[4];
  const float* W1   = (const float*)d_in[5];
  const float* b1   = (const float*)d_in[6];
  const float* p1wl = (const float*)d_in[7];
  const float* p1bl = (const float*)d_in[8];
  const float* p1wr = (const float*)d_in[9];
  const float* W2   = (const float*)d_in[10];
  const float* b2   = (const float*)d_in[11];
  const float* p2wl = (const float*)d_in[12];
  const float* p2bl = (const float*)d_in[13];
  const float* p2wr = (const float*)d_in[14];
  const float* W3   = (const float*)d_in[15];
  const float* b3   = (const float*)d_in[16];
  const float* p3wl = (const float*)d_in[17];
  const float* p3bl = (const float*)d_in[18];
  const float* p3wr = (const float*)d_in[19];
  const float* mW1  = (const float*)d_in[20];
  const float* mb1  = (const float*)d_in[21];
  const float* mW2  = (const float*)d_in[22];
  const float* mb2  = (const float*)d_in[23];
  const float* mW3  = (const float*)d_in[24];
  const float* mb3  = (const float*)d_in[25];
  float* out = (float*)d_out;

  const int B = in_sizes[0] / N0;  // 4096
  hipLaunchKernelGGL(sagpool_fused, dim3(B), dim3(TPB), 0, stream,
                     aa, pos, cdr, adj, emb,
                     W1, b1, p1wl, p1bl, p1wr,
                     W2, b2, p2wl, p2bl, p2wr,
                     W3, b3, p3wl, p3bl, p3wr,
                     mW1, mb1, mW2, mb2, mW3, mb3, out);
}